// Round 6
// baseline (232.253 us; speedup 1.0000x reference)
//
#include <hip/hip_runtime.h>
#include <hip/hip_bf16.h>

// TrendEncoder: histogram (B=4096, S=200 -> 256 bins) + 256-step LSTM (H=64).
// Round 6: R5 math + wave-pair duplication. 512 threads / 8 waves, wave pair
// (a, a+4) both compute the SAME 4 gate tiles for col-group 16a (MFMA pipe is
// ~10% busy -- duplication is free and parallel to VALU), then split the
// activation rows: waves 0-3 act rows 0-7, waves 4-7 act rows 8-15, using
// __shfl_xor(.,32) to fetch partner regs 2,3 (no LDS, no extra barrier).
// Act per lane: 2 units -> the transcendental issue (the dominant VALU term)
// halves per wave; 2 waves/SIMD overlap the ~47% stall half of the step.
// h carried in fp16 (single-MFMA path), fused shared-rcp activations with
// gate prescale folded into W/b (identical numerics to R5).

#define B_S     200
#define B_T     256
#define ROWS    16
#define THREADS 512
#define HS      72    // h row stride (fp16 elems) = 144 B
#define LOG2E   1.4426950408889634f

typedef __attribute__((ext_vector_type(8))) _Float16 half8;
typedef __attribute__((ext_vector_type(4))) float float4_t;

__device__ __forceinline__ float load_f(const void* p, int i, int isb) {
    if (isb) {
        unsigned short u = ((const unsigned short*)p)[i];
        return __uint_as_float(((unsigned int)u) << 16);
    }
    return ((const float*)p)[i];
}

__global__ __launch_bounds__(THREADS)
void trend_encoder_kernel(const void* __restrict__ time_,
                          const int*  __restrict__ length,
                          const void* __restrict__ ptime_,
                          const void* __restrict__ wih_,
                          const void* __restrict__ whh_,
                          const void* __restrict__ bih_,
                          const void* __restrict__ bhh_,
                          void* __restrict__ out_) {
    __shared__ __align__(16) float x_t[B_T * ROWS];            // [t][row], 16 KB
    __shared__ __align__(16) _Float16 h_sh[2][ROWS * HS];      // double-buffered
    __shared__ int flag_sh;

    const int tid  = threadIdx.x;
    const int wv   = tid >> 6;        // wave 0..7
    const int a    = wv & 3;          // col-group 16a
    const int W    = wv >> 2;         // act row half: 0 -> rows 0-7, 1 -> 8-15
    const int lane = tid & 63;
    const int m    = lane & 15;
    const int quad = lane >> 4;
    const int b0   = blockIdx.x * ROWS;

    // ---- dtype probe (wave 0): W_ih ~ U(-0.125,0.125); f32 reinterpreted as
    // bf16 words goes far out of range with overwhelming probability.
    if (tid < 64) {
        unsigned short u = ((const unsigned short*)wih_)[tid];
        float v = __uint_as_float(((unsigned int)u) << 16);
        int bad = !(v > -0.2f && v < 0.2f);
        unsigned long long bm = __ballot(bad);
        if (lane == 0) flag_sh = (bm == 0ULL) ? 1 : 0;
    }
    for (int i = tid; i < B_T * ROWS; i += THREADS) x_t[i] = 0.0f;
    for (int i = tid; i < ROWS * HS; i += THREADS) h_sh[0][i] = (_Float16)0.0f;
    __syncthreads();
    const int isb = flag_sh;

    // ---- histogram: pos = trunc((pt - t)*0.25), add at bin 255-pos (transposed)
    for (int e = tid; e < ROWS * B_S; e += THREADS) {
        int row  = e / B_S;
        int s    = e - row * B_S;
        int grow = b0 + row;
        if (s < length[grow]) {
            float pt = load_f(ptime_, grow, isb);
            float tv = load_f(time_, grow * B_S + s, isb);
            int pos = (int)((pt - tv) * 0.25f);
            if (pos >= 0 && pos < B_T)
                atomicAdd(&x_t[(B_T - 1 - pos) * ROWS + row], 1.0f);
        }
    }

    // ---- resident weights (fp16, gate-prescaled). tile tt = gate (i,f,g,o),
    // col n = 16a + 64tt + m.  B-frag: n = lane&15, k = 32c + 8*quad + j.
    const float gsc[4] = {-LOG2E, -LOG2E, 2.0f * LOG2E, -LOG2E};
    half8 bw[4][2];
    float wihv[4], biasv[4];
    #pragma unroll
    for (int tt = 0; tt < 4; ++tt) {
        int n = 16 * a + 64 * tt + m;
        float s = gsc[tt];
        wihv[tt]  = load_f(wih_, n, isb) * s;
        biasv[tt] = (load_f(bih_, n, isb) + load_f(bhh_, n, isb)) * s;
        #pragma unroll
        for (int c = 0; c < 2; ++c) {
            half8 v;
            #pragma unroll
            for (int j = 0; j < 8; ++j)
                v[j] = (_Float16)(load_f(whh_, n * 64 + 32 * c + 8 * quad + j, isb) * s);
            bw[tt][c] = v;
        }
    }

    const int aoff = m * HS + 8 * quad;   // A-frag base (elems)
    const int kcol = 16 * a + m;          // owned unit column
    // act ownership: qq = quad ^ (2W); own regs 0,1 if qq<2 else partner 2,3
    const int qq   = quad ^ (W << 1);
    const int row0 = W * 8 + (qq & 1) * 4 + ((qq >> 1) & 1) * 2;
    const bool own = (qq < 2);
    float c2[2] = {0.f, 0.f};
    float h2[2] = {0.f, 0.f};
    __syncthreads();   // histogram + h init + weights visible

    for (int t = 0; t < B_T; ++t) {
        const int p = t & 1;
        const _Float16* hh = h_sh[p];
        half8 a0 = *(const half8*)&hh[aoff];
        half8 a1 = *(const half8*)&hh[aoff + 32];
        float4_t xv = *(const float4_t*)&x_t[t * ROWS + quad * 4];

        float4_t acc[4];
        #pragma unroll
        for (int tt = 0; tt < 4; ++tt) {
            float4_t c;
            #pragma unroll
            for (int r = 0; r < 4; ++r) c[r] = fmaf(xv[r], wihv[tt], biasv[tt]);
            c = __builtin_amdgcn_mfma_f32_16x16x32_f16(a0, bw[tt][0], c, 0, 0, 0);
            c = __builtin_amdgcn_mfma_f32_16x16x32_f16(a1, bw[tt][1], c, 0, 0, 0);
            acc[tt] = c;
        }

        // redistribute: partner (lane^32) regs 2,3 carry this lane's rows
        float g0[4], g1[4];
        #pragma unroll
        for (int tt = 0; tt < 4; ++tt) {
            float s2 = __shfl_xor(acc[tt][2], 32);
            float s3 = __shfl_xor(acc[tt][3], 32);
            g0[tt] = own ? acc[tt][0] : s2;
            g1[tt] = own ? acc[tt][1] : s3;
        }

        // fused in-lane activation: 2 units (rows row0, row0+1; col kcol)
        _Float16* wb = h_sh[p ^ 1];
        #pragma unroll
        for (int k = 0; k < 2; ++k) {
            float gi = k ? g1[0] : g0[0];
            float gf = k ? g1[1] : g0[1];
            float gg = k ? g1[2] : g0[2];
            float go = k ? g1[3] : g0[3];
            float A  = __builtin_amdgcn_exp2f(gi);   // exp2(-i*log2e)
            float F  = __builtin_amdgcn_exp2f(gf);   // exp2(-f*log2e)
            float Bv = __builtin_amdgcn_exp2f(gg);   // exp2(2g*log2e)
            float t1    = (1.0f + A) * (Bv + 1.0f);
            float oneF  = 1.0f + F;
            float numer = fmaf(c2[k], t1, oneF * (Bv - 1.0f));
            float denom = oneF * t1;
            c2[k] = numer * __builtin_amdgcn_rcpf(denom);
            float D  = __builtin_amdgcn_exp2f(go);   // exp2(-o*log2e)
            float cs = fminf(c2[k] * (2.0f * LOG2E), 126.0f);  // inf guard
            float E  = __builtin_amdgcn_exp2f(cs);
            float h  = (E - 1.0f) * __builtin_amdgcn_rcpf((1.0f + D) * (E + 1.0f));
            h2[k] = h;
            wb[(row0 + k) * HS + kcol] = (_Float16)h;
        }
        __syncthreads();   // the only barrier per step
    }

    // ---- epilogue: final h of the 2 owned units
    #pragma unroll
    for (int k = 0; k < 2; ++k) {
        int o = (b0 + row0 + k) * 64 + kcol;
        if (isb) ((__hip_bfloat16*)out_)[o] = __float2bfloat16(h2[k]);
        else     ((float*)out_)[o] = h2[k];
    }
}

extern "C" void kernel_launch(void* const* d_in, const int* in_sizes, int n_in,
                              void* d_out, int out_size, void* d_ws, size_t ws_size,
                              hipStream_t stream) {
    const void* time_  = d_in[0];
    const int*  length = (const int*)d_in[1];
    const void* ptime  = d_in[2];
    const void* wih    = d_in[3];
    const void* whh    = d_in[4];
    const void* bih    = d_in[5];
    const void* bhh    = d_in[6];

    const int B = in_sizes[1];   // 4096
    trend_encoder_kernel<<<dim3(B / ROWS), dim3(THREADS), 0, stream>>>(
        time_, length, ptime, wih, whh, bih, bhh, d_out);
}